// Round 1
// baseline (154.372 us; speedup 1.0000x reference)
//
#include <hip/hip_runtime.h>

#define S0 4096
#define P0 64
#define S1 1024
#define P1 256
#define C  128
#define N_PTS (S0 * P0)

// ---------------------------------------------------------------------------
// Kernel A: per-segment assignment + scatter accumulation.
// One block per level0 segment. 256 threads = 4 waves; each wave handles 16
// points. Per point: coalesced float2/lane load of the 128-dim point feature,
// 3 dot products vs LDS-staged candidate center features, butterfly reduce,
// argmax -> assignment; coords accumulated in LDS per candidate slot.
// ---------------------------------------------------------------------------
__global__ __launch_bounds__(256) void assign_kernel(
    const float* __restrict__ sp_feat,   // [S1, C]
    const float* __restrict__ pts_feat,  // [S0, P0, C]
    const float* __restrict__ hilb,      // [N, 3]
    const int*   __restrict__ l01,       // [S0]
    float* __restrict__ out_assign,      // [N] (as float)
    float* __restrict__ ws_sum,          // [S1*3]
    float* __restrict__ ws_cnt)          // [S1]
{
    __shared__ float cf[3][C];
    __shared__ float lsum[3][3];
    __shared__ float lcnt[3];
    __shared__ int   lidx[3];

    const int s    = blockIdx.x;
    const int tid  = threadIdx.x;
    const int wave = tid >> 6;
    const int lane = tid & 63;

    if (tid == 0) {
        int sm = (s - 1 < 0) ? 0 : s - 1;
        int sp = (s + 1 >= S0) ? S0 - 1 : s + 1;
        lidx[0] = l01[sm];
        lidx[1] = l01[s];
        lidx[2] = l01[sp];
    }
    if (tid < 9) lsum[tid / 3][tid % 3] = 0.0f;
    if (tid < 3) lcnt[tid] = 0.0f;
    __syncthreads();

    // stage the 3 candidate center feature rows (1.5 KB)
    for (int i = tid; i < 3 * C; i += 256) {
        int k = i / C, c = i % C;
        cf[k][c] = sp_feat[(size_t)lidx[k] * C + c];
    }
    __syncthreads();

    const float* base = pts_feat + (size_t)s * P0 * C;
    const int c0 = lane * 2;

    for (int p = wave * 16; p < wave * 16 + 16; ++p) {
        float2 pf = *reinterpret_cast<const float2*>(base + p * C + c0);
        float d0 = pf.x * cf[0][c0] + pf.y * cf[0][c0 + 1];
        float d1 = pf.x * cf[1][c0] + pf.y * cf[1][c0 + 1];
        float d2 = pf.x * cf[2][c0] + pf.y * cf[2][c0 + 1];
        #pragma unroll
        for (int off = 32; off > 0; off >>= 1) {
            d0 += __shfl_xor(d0, off);
            d1 += __shfl_xor(d1, off);
            d2 += __shfl_xor(d2, off);
        }
        // all lanes hold the full sums; identical argmax everywhere.
        // Ties only occur between duplicate candidates (same sp id), so
        // lowest-k tie-break matches the reference's dist-ordered argmax.
        int kb = 0; float best = d0;
        if (d1 > best) { best = d1; kb = 1; }
        if (d2 > best) { best = d2; kb = 2; }

        const int flat = s * P0 + p;
        if (lane == 0) out_assign[flat] = (float)lidx[kb];
        if (lane < 3)  atomicAdd(&lsum[kb][lane], hilb[(size_t)flat * 3 + lane]);
        if (lane == 0) atomicAdd(&lcnt[kb], 1.0f);
    }
    __syncthreads();

    if (tid < 3) {
        atomicAdd(&ws_cnt[lidx[tid]], lcnt[tid]);
        #pragma unroll
        for (int c = 0; c < 3; ++c)
            atomicAdd(&ws_sum[(size_t)lidx[tid] * 3 + c], lsum[tid][c]);
    }
}

// ---------------------------------------------------------------------------
// Kernel B: finalize scatter-mean.
// ---------------------------------------------------------------------------
__global__ void finalize_kernel(const float* __restrict__ ws_sum,
                                const float* __restrict__ ws_cnt,
                                float* __restrict__ out_coord)
{
    int i = blockIdx.x * blockDim.x + threadIdx.x;
    if (i >= S1 * 3) return;
    int sp = i / 3;
    out_coord[i] = ws_sum[i] / fmaxf(ws_cnt[sp], 1.0f);
}

// ---------------------------------------------------------------------------
// Kernel C: bulk copies. rawPoint_feat -> outputs 3 and 4 (read once, write
// twice); sp_center_feat -> output 1. float4 grid-stride.
// ---------------------------------------------------------------------------
__global__ void copy_kernel(const float4* __restrict__ raw,
                            float4* __restrict__ o_pf,
                            float4* __restrict__ o_h1,
                            const float4* __restrict__ spf,
                            float4* __restrict__ o_spf)
{
    const long NR = (long)N_PTS * C / 4;  // 8388608
    const long NS = (long)S1 * C / 4;     // 32768
    for (long i = (long)blockIdx.x * blockDim.x + threadIdx.x;
         i < NR; i += (long)gridDim.x * blockDim.x) {
        float4 v = raw[i];
        o_pf[i] = v;
        o_h1[i] = v;
        if (i < NS) o_spf[i] = spf[i];
    }
}

extern "C" void kernel_launch(void* const* d_in, const int* in_sizes, int n_in,
                              void* d_out, int out_size, void* d_ws, size_t ws_size,
                              hipStream_t stream) {
    const float* sp_feat  = (const float*)d_in[0];
    // d_in[1] sp_center_coord: unused (only affects tie-order; proven irrelevant)
    const float* raw      = (const float*)d_in[2];
    const float* hilb     = (const float*)d_in[3];
    const float* pts_feat = (const float*)d_in[4];
    // d_in[5] points_coord: unused
    const int*   l01      = (const int*)d_in[6];

    float* out        = (float*)d_out;
    float* out_assign = out;                              // N
    float* out_spfeat = out_assign + N_PTS;               // S1*C
    float* out_coord  = out_spfeat + (size_t)S1 * C;      // S1*3
    float* out_pf     = out_coord + (size_t)S1 * 3;       // S0*P0*C
    float* out_h1     = out_pf + (size_t)S0 * P0 * C;     // S1*P1*C

    float* ws_sum = (float*)d_ws;            // S1*3
    float* ws_cnt = ws_sum + (size_t)S1 * 3; // S1

    hipMemsetAsync(d_ws, 0, (size_t)(S1 * 3 + S1) * sizeof(float), stream);

    assign_kernel<<<S0, 256, 0, stream>>>(sp_feat, pts_feat, hilb, l01,
                                          out_assign, ws_sum, ws_cnt);
    finalize_kernel<<<(S1 * 3 + 255) / 256, 256, 0, stream>>>(ws_sum, ws_cnt, out_coord);
    copy_kernel<<<2048, 256, 0, stream>>>(
        (const float4*)raw, (float4*)out_pf, (float4*)out_h1,
        (const float4*)sp_feat, (float4*)out_spfeat);
}

// Round 2
// 128.897 us; speedup vs baseline: 1.1976x; 1.1976x over previous
//
#include <hip/hip_runtime.h>

#define S0 4096
#define P0 64
#define S1 1024
#define P1 256
#define C  128
#define N_PTS (S0 * P0)

#define SEG_PER_BLK 4
#define PT_PER_BLK  256              // SEG_PER_BLK * P0
#define CHUNK       32               // channels staged per iteration
#define PSTRIDE     36               // LDS row stride (floats): mult of 4, ==4 mod 32 -> conflict-free b128

// ---------------------------------------------------------------------------
// Kernel A: assignment + scatter accumulation. One thread per point.
// Block covers 4 consecutive segments (256 points). Candidate superpoint rows
// for the block are l01[s_base-1 .. s_base+4] -> at most 6 distinct rows,
// staged once in LDS. points_feat staged in 32-channel chunks (coalesced
// float4), each thread accumulates 3 dots from registers. No shuffles.
// ---------------------------------------------------------------------------
__global__ __launch_bounds__(256) void assign_kernel(
    const float* __restrict__ sp_feat,   // [S1, C]
    const float* __restrict__ pts_feat,  // [S0, P0, C]
    const float* __restrict__ hilb,      // [N, 3]
    const int*   __restrict__ l01,       // [S0]
    float* __restrict__ out_assign,      // [N] (as float)
    float* __restrict__ ws_sum,          // [S1*3]
    float* __restrict__ ws_cnt)          // [S1]
{
    __shared__ float pt_lds[PT_PER_BLK * PSTRIDE]; // 36 KB
    __shared__ float cf_lds[6 * C];                // 3 KB: rows l01[s_base-1+j], j=0..5
    __shared__ float lsum[6][3];
    __shared__ float lcnt[6];
    __shared__ int   lidx[6];

    const int tid    = threadIdx.x;
    const int blk    = blockIdx.x;
    const int s_base = blk * SEG_PER_BLK;

    if (tid < 6) {
        int nb = s_base - 1 + tid;
        nb = nb < 0 ? 0 : (nb >= S0 ? S0 - 1 : nb);
        lidx[tid] = l01[nb];
        lcnt[tid] = 0.0f;
    }
    if (tid < 18) lsum[tid / 3][tid % 3] = 0.0f;
    __syncthreads();

    // stage the (<=6 distinct) candidate center rows
    for (int i = tid; i < 6 * C; i += 256)
        cf_lds[i] = sp_feat[(size_t)lidx[i >> 7] * C + (i & (C - 1))];
    // (ordered before first compute by the barrier inside the chunk loop)

    const size_t blk_base = (size_t)blk * PT_PER_BLK * C;
    const int    si       = tid >> 6;    // segment within block (wave-uniform)
    float d0 = 0.f, d1 = 0.f, d2 = 0.f;

    for (int ch = 0; ch < C; ch += CHUNK) {
        // ---- stage 256 points x 32 channels (coalesced float4) ----
        #pragma unroll
        for (int it = 0; it < 8; ++it) {
            int i  = tid + it * 256;          // 0..2047
            int pt = i >> 3, q = i & 7;
            float4 v = *reinterpret_cast<const float4*>(
                pts_feat + blk_base + (size_t)pt * C + ch + q * 4);
            *reinterpret_cast<float4*>(&pt_lds[pt * PSTRIDE + q * 4]) = v;
        }
        __syncthreads();

        // ---- per-thread dot accumulation ----
        const float* prow = &pt_lds[tid * PSTRIDE];
        const float* c0   = &cf_lds[(si + 0) * C + ch];
        const float* c1   = &cf_lds[(si + 1) * C + ch];
        const float* c2   = &cf_lds[(si + 2) * C + ch];
        #pragma unroll
        for (int j = 0; j < CHUNK; j += 4) {
            float4 v  = *reinterpret_cast<const float4*>(prow + j);
            float4 a0 = *reinterpret_cast<const float4*>(c0 + j);
            float4 a1 = *reinterpret_cast<const float4*>(c1 + j);
            float4 a2 = *reinterpret_cast<const float4*>(c2 + j);
            d0 += v.x * a0.x + v.y * a0.y + v.z * a0.z + v.w * a0.w;
            d1 += v.x * a1.x + v.y * a1.y + v.z * a1.z + v.w * a1.w;
            d2 += v.x * a2.x + v.y * a2.y + v.z * a2.z + v.w * a2.w;
        }
        __syncthreads();
    }

    // argmax (ties only between duplicate candidate ids -> any pick correct)
    int kb = 0; float best = d0;
    if (d1 > best) { best = d1; kb = 1; }
    if (d2 > best) { best = d2; kb = 2; }
    const int slot = si + kb;                  // candidate row index in block
    const int gpt  = blk * PT_PER_BLK + tid;

    out_assign[gpt] = (float)lidx[slot];

    const float hx = hilb[(size_t)gpt * 3 + 0];
    const float hy = hilb[(size_t)gpt * 3 + 1];
    const float hz = hilb[(size_t)gpt * 3 + 2];
    atomicAdd(&lsum[slot][0], hx);
    atomicAdd(&lsum[slot][1], hy);
    atomicAdd(&lsum[slot][2], hz);
    atomicAdd(&lcnt[slot], 1.0f);
    __syncthreads();

    if (tid < 6 && lcnt[tid] > 0.0f) {
        atomicAdd(&ws_cnt[lidx[tid]], lcnt[tid]);
        atomicAdd(&ws_sum[(size_t)lidx[tid] * 3 + 0], lsum[tid][0]);
        atomicAdd(&ws_sum[(size_t)lidx[tid] * 3 + 1], lsum[tid][1]);
        atomicAdd(&ws_sum[(size_t)lidx[tid] * 3 + 2], lsum[tid][2]);
    }
}

// ---------------------------------------------------------------------------
// Kernel B: bulk copies + fused scatter-mean finalize.
// rawPoint_feat -> outputs 3 and 4 (read once, write twice);
// sp_center_feat -> output 1; first 3072 threads finalize new centers.
// ---------------------------------------------------------------------------
__global__ void copy_kernel(const float4* __restrict__ raw,
                            float4* __restrict__ o_pf,
                            float4* __restrict__ o_h1,
                            const float4* __restrict__ spf,
                            float4* __restrict__ o_spf,
                            const float* __restrict__ ws_sum,
                            const float* __restrict__ ws_cnt,
                            float* __restrict__ out_coord)
{
    const long gid = (long)blockIdx.x * blockDim.x + threadIdx.x;
    if (gid < S1 * 3)
        out_coord[gid] = ws_sum[gid] / fmaxf(ws_cnt[gid / 3], 1.0f);

    const long NR = (long)N_PTS * C / 4;  // 8388608
    const long NS = (long)S1 * C / 4;     // 32768
    for (long i = gid; i < NR; i += (long)gridDim.x * blockDim.x) {
        float4 v = raw[i];
        o_pf[i] = v;
        o_h1[i] = v;
        if (i < NS) o_spf[i] = spf[i];
    }
}

extern "C" void kernel_launch(void* const* d_in, const int* in_sizes, int n_in,
                              void* d_out, int out_size, void* d_ws, size_t ws_size,
                              hipStream_t stream) {
    const float* sp_feat  = (const float*)d_in[0];
    // d_in[1] sp_center_coord: unused (only affects tie-order among duplicates)
    const float* raw      = (const float*)d_in[2];
    const float* hilb     = (const float*)d_in[3];
    const float* pts_feat = (const float*)d_in[4];
    // d_in[5] points_coord: unused
    const int*   l01      = (const int*)d_in[6];

    float* out        = (float*)d_out;
    float* out_assign = out;                              // N
    float* out_spfeat = out_assign + N_PTS;               // S1*C
    float* out_coord  = out_spfeat + (size_t)S1 * C;      // S1*3
    float* out_pf     = out_coord + (size_t)S1 * 3;       // S0*P0*C
    float* out_h1     = out_pf + (size_t)S0 * P0 * C;     // S1*P1*C

    float* ws_sum = (float*)d_ws;            // S1*3
    float* ws_cnt = ws_sum + (size_t)S1 * 3; // S1

    hipMemsetAsync(d_ws, 0, (size_t)(S1 * 3 + S1) * sizeof(float), stream);

    assign_kernel<<<S0 / SEG_PER_BLK, 256, 0, stream>>>(
        sp_feat, pts_feat, hilb, l01, out_assign, ws_sum, ws_cnt);

    copy_kernel<<<2048, 256, 0, stream>>>(
        (const float4*)raw, (float4*)out_pf, (float4*)out_h1,
        (const float4*)sp_feat, (float4*)out_spfeat,
        ws_sum, ws_cnt, out_coord);
}

// Round 3
// 128.064 us; speedup vs baseline: 1.2054x; 1.0065x over previous
//
#include <hip/hip_runtime.h>

#define S0 4096
#define P0 64
#define S1 1024
#define P1 256
#define C  128
#define N_PTS (S0 * P0)

#define SEG_PER_BLK   4
#define PT_PER_BLK    256                    // SEG_PER_BLK * P0
#define ASSIGN_BLOCKS (S0 / SEG_PER_BLK)     // 1024
#define TOTAL_BLOCKS  2048                   // 8 blocks/CU * 256 CU -> whole grid resident

// ---------------------------------------------------------------------------
// Fused kernel.
// Blocks 0..1023: assignment for 4 consecutive segments (1 thread = 1 point,
//   direct global row reads, register dots vs LDS-broadcast candidate rows,
//   LDS-aggregated scatter sums), then join the grid-stride copy.
// Blocks 1024..2047: copy only (start writing immediately -> read/write mix).
// ---------------------------------------------------------------------------
__global__ __launch_bounds__(256) void fused_kernel(
    const float* __restrict__ sp_feat,   // [S1, C]
    const float* __restrict__ pts_feat,  // [S0, P0, C]
    const float* __restrict__ hilb,      // [N, 3]
    const int*   __restrict__ l01,       // [S0]
    const float4* __restrict__ raw,      // [N*C/4]
    float*  __restrict__ out_assign,     // [N] (as float)
    float4* __restrict__ o_pf,           // [N*C/4]
    float4* __restrict__ o_h1,           // [N*C/4]
    float4* __restrict__ o_spf,          // [S1*C/4]
    float*  __restrict__ ws_sum,         // [S1*3]
    float*  __restrict__ ws_cnt)         // [S1]
{
    __shared__ float cf_lds[6 * C];   // candidate rows l01[s_base-1 .. s_base+4]
    __shared__ float lsum[6][3];
    __shared__ float lcnt[6];
    __shared__ int   lidx[6];

    const int tid = threadIdx.x;
    const int blk = blockIdx.x;

    if (blk < ASSIGN_BLOCKS) {
        const int s_base = blk * SEG_PER_BLK;
        if (tid < 6) {
            int nb = s_base - 1 + tid;
            nb = nb < 0 ? 0 : (nb >= S0 ? S0 - 1 : nb);
            lidx[tid] = l01[nb];
            lcnt[tid] = 0.0f;
        }
        if (tid < 18) lsum[tid / 3][tid % 3] = 0.0f;
        __syncthreads();

        for (int i = tid; i < 6 * C; i += 256)
            cf_lds[i] = sp_feat[(size_t)lidx[i >> 7] * C + (i & (C - 1))];
        __syncthreads();

        const int si  = tid >> 6;                 // wave-uniform segment slot
        const int gpt = blk * PT_PER_BLK + tid;
        const float* prow = pts_feat + (size_t)gpt * C;
        const float* c0 = &cf_lds[(si + 0) * C];
        const float* c1 = &cf_lds[(si + 1) * C];
        const float* c2 = &cf_lds[(si + 2) * C];

        float d0 = 0.f, d1 = 0.f, d2 = 0.f;
        #pragma unroll
        for (int j = 0; j < C; j += 4) {
            float4 v  = *reinterpret_cast<const float4*>(prow + j);
            float4 a0 = *reinterpret_cast<const float4*>(c0 + j);
            float4 a1 = *reinterpret_cast<const float4*>(c1 + j);
            float4 a2 = *reinterpret_cast<const float4*>(c2 + j);
            d0 += v.x * a0.x + v.y * a0.y + v.z * a0.z + v.w * a0.w;
            d1 += v.x * a1.x + v.y * a1.y + v.z * a1.z + v.w * a1.w;
            d2 += v.x * a2.x + v.y * a2.y + v.z * a2.z + v.w * a2.w;
        }

        // argmax; ties only between duplicate candidate ids -> any pick correct
        int kb = 0; float best = d0;
        if (d1 > best) { best = d1; kb = 1; }
        if (d2 > best) { best = d2; kb = 2; }
        const int slot = si + kb;

        out_assign[gpt] = (float)lidx[slot];

        atomicAdd(&lsum[slot][0], hilb[(size_t)gpt * 3 + 0]);
        atomicAdd(&lsum[slot][1], hilb[(size_t)gpt * 3 + 1]);
        atomicAdd(&lsum[slot][2], hilb[(size_t)gpt * 3 + 2]);
        atomicAdd(&lcnt[slot], 1.0f);
        __syncthreads();

        if (tid < 6 && lcnt[tid] > 0.0f) {
            atomicAdd(&ws_cnt[lidx[tid]], lcnt[tid]);
            atomicAdd(&ws_sum[(size_t)lidx[tid] * 3 + 0], lsum[tid][0]);
            atomicAdd(&ws_sum[(size_t)lidx[tid] * 3 + 1], lsum[tid][1]);
            atomicAdd(&ws_sum[(size_t)lidx[tid] * 3 + 2], lsum[tid][2]);
        }
    }

    // ---- copy phase: all blocks, grid-stride (16 iterations exactly) ----
    const long NR = (long)N_PTS * C / 4;   // 8388608
    const long NS = (long)S1 * C / 4;      // 32768
    const long gid    = (long)blk * 256 + tid;
    const long stride = (long)TOTAL_BLOCKS * 256;
    const float4* spf4 = (const float4*)sp_feat;
    for (long i = gid; i < NR; i += stride) {
        float4 v = raw[i];
        o_pf[i] = v;
        o_h1[i] = v;
        if (i < NS) o_spf[i] = spf4[i];
    }
}

// ---------------------------------------------------------------------------
// Finalize scatter-mean (after all atomics).
// ---------------------------------------------------------------------------
__global__ void finalize_kernel(const float* __restrict__ ws_sum,
                                const float* __restrict__ ws_cnt,
                                float* __restrict__ out_coord)
{
    int i = blockIdx.x * blockDim.x + threadIdx.x;
    if (i >= S1 * 3) return;
    out_coord[i] = ws_sum[i] / fmaxf(ws_cnt[i / 3], 1.0f);
}

extern "C" void kernel_launch(void* const* d_in, const int* in_sizes, int n_in,
                              void* d_out, int out_size, void* d_ws, size_t ws_size,
                              hipStream_t stream) {
    const float* sp_feat  = (const float*)d_in[0];
    // d_in[1] sp_center_coord: unused (only affects tie-order among duplicates)
    const float* raw      = (const float*)d_in[2];
    const float* hilb     = (const float*)d_in[3];
    const float* pts_feat = (const float*)d_in[4];
    // d_in[5] points_coord: unused
    const int*   l01      = (const int*)d_in[6];

    float* out        = (float*)d_out;
    float* out_assign = out;                              // N
    float* out_spfeat = out_assign + N_PTS;               // S1*C
    float* out_coord  = out_spfeat + (size_t)S1 * C;      // S1*3
    float* out_pf     = out_coord + (size_t)S1 * 3;       // S0*P0*C
    float* out_h1     = out_pf + (size_t)S0 * P0 * C;     // S1*P1*C

    float* ws_sum = (float*)d_ws;            // S1*3
    float* ws_cnt = ws_sum + (size_t)S1 * 3; // S1

    hipMemsetAsync(d_ws, 0, (size_t)(S1 * 3 + S1) * sizeof(float), stream);

    fused_kernel<<<TOTAL_BLOCKS, 256, 0, stream>>>(
        sp_feat, pts_feat, hilb, l01, (const float4*)raw,
        out_assign, (float4*)out_pf, (float4*)out_h1, (float4*)out_spfeat,
        ws_sum, ws_cnt);

    finalize_kernel<<<(S1 * 3 + 255) / 256, 256, 0, stream>>>(ws_sum, ws_cnt, out_coord);
}

// Round 4
// 127.224 us; speedup vs baseline: 1.2134x; 1.0066x over previous
//
#include <hip/hip_runtime.h>

#define S0 4096
#define P0 64
#define S1 1024
#define P1 256
#define C  128
#define N_PTS (S0 * P0)

#define SEG_PER_BLK   4                      // 1 segment per wave
#define ASSIGN_BLOCKS (S0 / SEG_PER_BLK)     // 1024
#define TOTAL_BLOCKS  2048

// ---------------------------------------------------------------------------
// Fused kernel.
// Blocks 0..1023: assignment, wave-cooperative. Each wave owns one segment
//   (64 points x 128 ch). The segment is read in 32 coalesced 1-KB steps;
//   step k delivers row 2k to lanes 0-31 and row 2k+1 to lanes 32-63
//   (4 channels per lane). Each half reduces its row's 3 candidate dots via
//   5 intra-half shfl_xor steps. Candidate features live in 12 registers per
//   lane (each lane only needs its own 4 channels). No barriers in the loop.
// Blocks 1024..2047: copy only. All blocks join the grid-stride copy.
// ---------------------------------------------------------------------------
__global__ __launch_bounds__(256) void fused_kernel(
    const float* __restrict__ sp_feat,   // [S1, C]
    const float* __restrict__ pts_feat,  // [S0, P0, C]
    const float* __restrict__ hilb,      // [N, 3]
    const int*   __restrict__ l01,       // [S0]
    const float4* __restrict__ raw,      // [N*C/4]
    float*  __restrict__ out_assign,     // [N] (as float)
    float4* __restrict__ o_pf,           // [N*C/4]
    float4* __restrict__ o_h1,           // [N*C/4]
    float4* __restrict__ o_spf,          // [S1*C/4]
    float*  __restrict__ ws_sum,         // [S1*3]
    float*  __restrict__ ws_cnt)         // [S1]
{
    __shared__ float lsum[4][3][3];   // [wave][cand][xyz]
    __shared__ float lcnt[4][3];

    const int tid  = threadIdx.x;
    const int blk  = blockIdx.x;
    const int w    = tid >> 6;
    const int lane = tid & 63;

    if (blk < ASSIGN_BLOCKS) {
        if (tid < 36) ((float*)lsum)[tid] = 0.0f;
        if (tid < 12) ((float*)lcnt)[tid] = 0.0f;
        __syncthreads();

        const int s  = blk * SEG_PER_BLK + w;
        const int sm = (s - 1 < 0) ? 0 : s - 1;
        const int sp = (s + 1 >= S0) ? S0 - 1 : s + 1;
        const int id0 = l01[sm], id1 = l01[s], id2 = l01[sp];

        const int h = lane >> 5;             // which row of the 2-row window
        const int q = (lane & 31) * 4;       // this lane's 4 channels

        const float4 c0 = *reinterpret_cast<const float4*>(sp_feat + (size_t)id0 * C + q);
        const float4 c1 = *reinterpret_cast<const float4*>(sp_feat + (size_t)id1 * C + q);
        const float4 c2 = *reinterpret_cast<const float4*>(sp_feat + (size_t)id2 * C + q);

        const float* segb = pts_feat + (size_t)s * P0 * C;

        #pragma unroll 4
        for (int k = 0; k < 32; ++k) {
            const int row = 2 * k + h;
            float4 v = *reinterpret_cast<const float4*>(segb + (size_t)row * C + q);
            float p0 = v.x * c0.x + v.y * c0.y + v.z * c0.z + v.w * c0.w;
            float p1 = v.x * c1.x + v.y * c1.y + v.z * c1.z + v.w * c1.w;
            float p2 = v.x * c2.x + v.y * c2.y + v.z * c2.z + v.w * c2.w;
            #pragma unroll
            for (int off = 1; off < 32; off <<= 1) {   // stays within each half
                p0 += __shfl_xor(p0, off);
                p1 += __shfl_xor(p1, off);
                p2 += __shfl_xor(p2, off);
            }
            if ((lane & 31) == 0) {
                int kb = 0; float best = p0;
                if (p1 > best) { best = p1; kb = 1; }
                if (p2 > best) { best = p2; kb = 2; }
                const int gpt = s * P0 + row;
                out_assign[gpt] = (float)(kb == 0 ? id0 : (kb == 1 ? id1 : id2));
                const float* hp = hilb + (size_t)gpt * 3;
                atomicAdd(&lsum[w][kb][0], hp[0]);
                atomicAdd(&lsum[w][kb][1], hp[1]);
                atomicAdd(&lsum[w][kb][2], hp[2]);
                atomicAdd(&lcnt[w][kb], 1.0f);
            }
        }
        __syncthreads();

        if (tid < 12) {
            const int ww = tid >> 2;          // 0..2 waves per... no: 12 = 4x3
        }
        if (tid < 12) {
            const int ww = tid / 3, kb = tid % 3;
            if (lcnt[ww][kb] > 0.0f) {
                const int s2 = blk * SEG_PER_BLK + ww;
                int nb = s2 - 1 + kb;
                nb = nb < 0 ? 0 : (nb >= S0 ? S0 - 1 : nb);
                const int id = l01[nb];
                atomicAdd(&ws_cnt[id], lcnt[ww][kb]);
                atomicAdd(&ws_sum[(size_t)id * 3 + 0], lsum[ww][kb][0]);
                atomicAdd(&ws_sum[(size_t)id * 3 + 1], lsum[ww][kb][1]);
                atomicAdd(&ws_sum[(size_t)id * 3 + 2], lsum[ww][kb][2]);
            }
        }
    }

    // ---- copy phase: all blocks, grid-stride ----
    const long NR = (long)N_PTS * C / 4;   // 8388608
    const long NS = (long)S1 * C / 4;      // 32768
    const long gid    = (long)blk * 256 + tid;
    const long stride = (long)TOTAL_BLOCKS * 256;
    const float4* spf4 = (const float4*)sp_feat;
    for (long i = gid; i < NR; i += stride) {
        float4 v = raw[i];
        o_pf[i] = v;
        o_h1[i] = v;
        if (i < NS) o_spf[i] = spf4[i];
    }
}

// ---------------------------------------------------------------------------
// Finalize scatter-mean (after all atomics).
// ---------------------------------------------------------------------------
__global__ void finalize_kernel(const float* __restrict__ ws_sum,
                                const float* __restrict__ ws_cnt,
                                float* __restrict__ out_coord)
{
    int i = blockIdx.x * blockDim.x + threadIdx.x;
    if (i >= S1 * 3) return;
    out_coord[i] = ws_sum[i] / fmaxf(ws_cnt[i / 3], 1.0f);
}

extern "C" void kernel_launch(void* const* d_in, const int* in_sizes, int n_in,
                              void* d_out, int out_size, void* d_ws, size_t ws_size,
                              hipStream_t stream) {
    const float* sp_feat  = (const float*)d_in[0];
    // d_in[1] sp_center_coord: unused (only affects tie-order among duplicates)
    const float* raw      = (const float*)d_in[2];
    const float* hilb     = (const float*)d_in[3];
    const float* pts_feat = (const float*)d_in[4];
    // d_in[5] points_coord: unused
    const int*   l01      = (const int*)d_in[6];

    float* out        = (float*)d_out;
    float* out_assign = out;                              // N
    float* out_spfeat = out_assign + N_PTS;               // S1*C
    float* out_coord  = out_spfeat + (size_t)S1 * C;      // S1*3
    float* out_pf     = out_coord + (size_t)S1 * 3;       // S0*P0*C
    float* out_h1     = out_pf + (size_t)S0 * P0 * C;     // S1*P1*C

    float* ws_sum = (float*)d_ws;            // S1*3
    float* ws_cnt = ws_sum + (size_t)S1 * 3; // S1

    hipMemsetAsync(d_ws, 0, (size_t)(S1 * 3 + S1) * sizeof(float), stream);

    fused_kernel<<<TOTAL_BLOCKS, 256, 0, stream>>>(
        sp_feat, pts_feat, hilb, l01, (const float4*)raw,
        out_assign, (float4*)out_pf, (float4*)out_h1, (float4*)out_spfeat,
        ws_sum, ws_cnt);

    finalize_kernel<<<(S1 * 3 + 255) / 256, 256, 0, stream>>>(ws_sum, ws_cnt, out_coord);
}